// Round 17
// baseline (80.401 us; speedup 1.0000x reference)
//
#include <hip/hip_runtime.h>

// LocalCrossCorrelation3D: I,J (2,1,96,192,192) fp32 -> (loss[2], cc[2,81,192,192])
// Window (16,9,9): depth valid (96->81), h/w zero-padded +-4.
// K1 = SINGLE-WAVE blocks (zero barriers): 4 w-tiles x {56 outputs + 8 halo
// lanes}; depth sliding sum in regs (1-ahead prefetch); 9-tap w-box as two
// 3-tap stages through wave-synchronous LDS (DS ops in-order within a wave),
// own-lane values kept in registers. ws = AoS uint3 bf16 (12B/voxel).
// K2 = h sliding box, full unroll + static ring + spread-slot loss atomics.
// K3 = slot reduce.

constexpr int N = 2, D = 96, H = 192, W = 192;
constexpr int OD = 81;            // D - 16 + 1
constexpr int KD = 16;
constexpr int HWp = H * W;        // 36864
constexpr float INV_WIN = 1.0f / 1296.0f;
constexpr float EPS_NZ = 3.0590232050182579e-07f;  // e^-15
constexpr int CH = 24;            // h-chunk per block in K2 (192/24 = 8)
constexpr int ODPB = 14;          // od-range per K1 block

__device__ __forceinline__ unsigned bf16rne(float f) {  // f32 -> bf16 bits (RNE)
  unsigned u = __float_as_uint(f);
  return (u + 0x7fffu + ((u >> 16) & 1u)) >> 16;
}
__device__ __forceinline__ float bf16tof(unsigned h) {  // bf16 bits -> f32
  return __uint_as_float(h << 16);
}

// ---------------------------------------------------------------------------
// K1. One wave per block. Lane l of tile t covers column wcol = t*56 + l - 4
// (lanes 4..59 are outputs; l<4 / l>=60 redundant halo). Per od:
//   x[l] = 5-ch depth sums (post-add snapshot), written to LDS;
//   stage1: A[l] = x[l-1]+x[l]+x[l+1]  (own x in regs, read x[l+-1]);
//   stage2: S[l] = A[l-3]+A[l]+A[l+3]  (own A in regs, read A[l+-3]).
// Wrap ((l+-k)&63) garbage reaches only A[0]/A[63], consumed only by lanes
// 3/60 -> non-output lanes. Out-of-range columns load 0 (zero-pad semantics).
// NO barriers: DS ops from a single wave execute in order; compiler inserts
// lgkmcnt waits for read results (dynamic indices force conservative alias).
// ws layout: [n][odi][h][w] x 3 uints (bf16 pairs: (s0,s1),(s2,s3),(s4,_)).
__global__ __launch_bounds__(64)
void k_dw(const float* __restrict__ I, const float* __restrict__ J,
          unsigned* __restrict__ ws, int od0, int c, int odcStride) {
  const int h = blockIdx.x >> 2;
  const int tile = blockIdx.x & 3;
  const int n = blockIdx.z;
  const int os = od0 + blockIdx.y * ODPB;
  int oe = od0 + c; if (os + ODPB < oe) oe = os + ODPB;
  if (os >= oe) return;

  const int lane = threadIdx.x;               // 0..63
  const int wcol = tile * 56 + lane - 4;      // -4 .. 227
  const bool colOK = (wcol >= 0) && (wcol < W);
  const bool stOK  = (lane >= 4) && (lane < 60) && (wcol < W);

  __shared__ float4 x4[64]; __shared__ float x1[64];
  __shared__ float4 a4[64]; __shared__ float a1[64];

  const size_t colBase = ((size_t)n * D * H + h) * (size_t)W + wcol;
  const float* Ip = I + colBase;
  const float* Jp = J + colBase;
  unsigned* wbase = ws + ((size_t)n * odcStride * HWp + (size_t)h * W + wcol) * 3;

  const int lm1 = (lane - 1) & 63, lp1 = (lane + 1) & 63;
  const int lm3 = (lane - 3) & 63, lp3 = (lane + 3) & 63;

  // warm-up: accumulate slices [os, os+KD-2] (15 slices)
  float sI = 0.f, sJ = 0.f, sII = 0.f, sJJ = 0.f, sIJ = 0.f;
  for (int d = os; d < os + KD - 1; ++d) {
    const float iv = colOK ? Ip[(size_t)d * HWp] : 0.f;
    const float jv = colOK ? Jp[(size_t)d * HWp] : 0.f;
    sI += iv; sJ += jv;
    sII += iv * iv; sJJ += jv * jv; sIJ += iv * jv;
  }

  // prefetch first round: entering od+15, leaving od
  float eI = colOK ? Ip[(size_t)(os + KD - 1) * HWp] : 0.f;
  float eJ = colOK ? Jp[(size_t)(os + KD - 1) * HWp] : 0.f;
  float lI = colOK ? Ip[(size_t)os * HWp] : 0.f;
  float lJ = colOK ? Jp[(size_t)os * HWp] : 0.f;

  for (int od = os; od < oe; ++od) {
    const float ceI = eI, ceJ = eJ, clI = lI, clJ = lJ;
    const int odn = od + 1;
    if (odn < oe) {   // prefetch next round (awaited next iteration)
      eI = colOK ? Ip[(size_t)(odn + KD - 1) * HWp] : 0.f;
      eJ = colOK ? Jp[(size_t)(odn + KD - 1) * HWp] : 0.f;
      lI = colOK ? Ip[(size_t)odn * HWp] : 0.f;
      lJ = colOK ? Jp[(size_t)odn * HWp] : 0.f;
    }
    // snapshot (post-add)
    sI += ceI; sJ += ceJ;
    sII += ceI * ceI; sJJ += ceJ * ceJ; sIJ += ceI * ceJ;
    const float cI = sI, cJ = sJ, cII = sII, cJJ = sJJ, cIJ = sIJ;
    x4[lane] = make_float4(cI, cJ, cII, cJJ); x1[lane] = cIJ;
    sI -= clI; sJ -= clJ;
    sII -= clI * clI; sJJ -= clJ * clJ; sIJ -= clI * clJ;

    // stage 1: A = x[l-1] + x(own) + x[l+1]
    const float4 m0 = x4[lm1], m2 = x4[lp1];
    const float  p0 = x1[lm1], p2 = x1[lp1];
    const float aI  = m0.x + cI  + m2.x;
    const float aJ  = m0.y + cJ  + m2.y;
    const float aII = m0.z + cII + m2.z;
    const float aJJ = m0.w + cJJ + m2.w;
    const float aIJ = p0   + cIJ + p2;
    a4[lane] = make_float4(aI, aJ, aII, aJJ); a1[lane] = aIJ;

    // stage 2: S = A[l-3] + A(own) + A[l+3]
    const float4 b0 = a4[lm3], b2 = a4[lp3];
    const float  q0 = a1[lm3], q2 = a1[lp3];
    const float r0 = b0.x + aI  + b2.x;
    const float r1 = b0.y + aJ  + b2.y;
    const float r2 = b0.z + aII + b2.z;
    const float r3 = b0.w + aJJ + b2.w;
    const float r4 = q0   + aIJ + q2;

    if (stOK) {
      unsigned* o = wbase + (size_t)(od - od0) * HWp * 3;
      o[0] = bf16rne(r0) | (bf16rne(r1) << 16);
      o[1] = bf16rne(r2) | (bf16rne(r3) << 16);
      o[2] = bf16rne(r4);
    }
  }
}

// ---------------------------------------------------------------------------
// K2: 9-wide h box via fully-unrolled stream with an 8-deep static ring
// (no subtract re-loads) + one-ahead prefetch; cc formula + loss reduction.
// Loss partial -> one of 32 spread slots per batch (atomic line-spread).
// Block: 192 threads = w-row, grid (od, h-chunk of 24, n).
__global__ __launch_bounds__(192)
void k_hcc(const unsigned* __restrict__ ws, float* __restrict__ cc,
           float* __restrict__ acc, int od0, int odcStride) {
  const int odi = blockIdx.x;
  const int od = od0 + odi;
  const int h0 = blockIdx.y * CH;
  const int n = blockIdx.z;
  const int w = threadIdx.x;
  const unsigned* base =
      ws + ((size_t)n * odcStride * HWp + (size_t)odi * HWp + w) * 3;
  float* ccp = cc + ((size_t)n * OD + od) * (size_t)HWp + w;

  float s0 = 0.f, s1 = 0.f, s2 = 0.f, s3 = 0.f, s4 = 0.f;
  float lsum = 0.f;
  uint3 hist[8];
  const uint3 z3 = make_uint3(0u, 0u, 0u);

  // prefetch t=0 row
  uint3 vN = z3;
  {
    const int hin = h0 - 4;
    if (hin >= 0) vN = *(const uint3*)(base + (size_t)hin * W * 3);
  }
#pragma unroll
  for (int t = 0; t < CH + 8; ++t) {
    const uint3 v = vN;
    // prefetch next row
    if (t + 1 < CH + 8) {
      const int hn = h0 - 4 + t + 1;
      vN = (hn >= 0 && hn < H) ? *(const uint3*)(base + (size_t)hn * W * 3) : z3;
    }
    s0 += bf16tof(v.x & 0xffffu); s1 += bf16tof(v.x >> 16);
    s2 += bf16tof(v.y & 0xffffu); s3 += bf16tof(v.y >> 16);
    s4 += bf16tof(v.z & 0xffffu);
    if (t >= 8) {
      const int h = h0 + t - 8;
      const float cross = s4 - s0 * s1 * INV_WIN;
      const float vI = s2 - s0 * s0 * INV_WIN;
      const float vJ = s3 - s1 * s1 * INV_WIN;
      const float prod = vI * vJ;
      const float c = (prod > EPS_NZ) ? (cross * cross) / (prod + EPS_NZ)
                                      : 1.0f / (1.0f + EPS_NZ);
      ccp[(size_t)h * W] = c;
      lsum += c;
      const uint3 q = hist[t & 7];       // row that entered 8 steps ago
      s0 -= bf16tof(q.x & 0xffffu); s1 -= bf16tof(q.x >> 16);
      s2 -= bf16tof(q.y & 0xffffu); s3 -= bf16tof(q.y >> 16);
      s4 -= bf16tof(q.z & 0xffffu);
    }
    hist[t & 7] = v;                     // static index (full unroll)
  }
  __shared__ float red[3];
#pragma unroll
  for (int off = 32; off > 0; off >>= 1) lsum += __shfl_xor(lsum, off, 64);
  if ((threadIdx.x & 63) == 0) red[threadIdx.x >> 6] = lsum;
  __syncthreads();
  if (threadIdx.x == 0)
    atomicAdd(acc + n * 32 + (odi & 31), red[0] + red[1] + red[2]);
}

// ---------------------------------------------------------------------------
// K3: reduce the 64 spread slots (32 per batch) -> loss.
__global__ void k_fin(const float* __restrict__ acc, float* __restrict__ out) {
  const int t = threadIdx.x;            // 64 threads
  float v = acc[t];                     // slots [n*32 + k]
#pragma unroll
  for (int off = 16; off > 0; off >>= 1) v += __shfl_xor(v, off, 32);
  if (t == 0)  out[0] = 1.0f - v * (1.0f / 2985984.0f);
  if (t == 32) out[1] = 1.0f - v * (1.0f / 2985984.0f);
}

// ---------------------------------------------------------------------------
extern "C" void kernel_launch(void* const* d_in, const int* in_sizes, int n_in,
                              void* d_out, int out_size, void* d_ws,
                              size_t ws_size, hipStream_t stream) {
  const float* I = (const float*)d_in[0];
  const float* J = (const float*)d_in[1];
  float* out = (float*)d_out;
  float* acc = (float*)d_ws;                       // 64 fp32 spread slots
  unsigned* planes = (unsigned*)((char*)d_ws + 256);

  hipMemsetAsync(d_ws, 0, 64 * sizeof(float), stream);

  // adaptive od-chunking: packed voxel = 12B, two n-slabs
  const size_t perOdPerN = (size_t)HWp * 12;       // 442368 B
  size_t avail = (ws_size > 256) ? (ws_size - 256) : 0;
  long long odcMax = (long long)(avail / (2 * perOdPerN));
  if (odcMax < 1) odcMax = 1;
  if (odcMax > OD) odcMax = OD;
  const int odc = (int)odcMax;                     // slab stride (od entries)

  float* ccOut = out + 2;
  for (int od0 = 0; od0 < OD; od0 += odc) {
    const int c = (odc < OD - od0) ? odc : (OD - od0);
    const int S = (c + ODPB - 1) / ODPB;
    hipLaunchKernelGGL(k_dw, dim3(H * 4, S, N), dim3(64), 0, stream,
                       I, J, planes, od0, c, odc);
    hipLaunchKernelGGL(k_hcc, dim3(c, H / CH, N), dim3(192), 0, stream,
                       planes, ccOut, acc, od0, odc);
  }
  hipLaunchKernelGGL(k_fin, dim3(1), dim3(64), 0, stream, acc, out);
}

// Round 18
// 71.120 us; speedup vs baseline: 1.1305x; 1.1305x over previous
//
#include <hip/hip_runtime.h>

// LocalCrossCorrelation3D: I,J (2,1,96,192,192) fp32 -> (loss[2], cc[2,81,192,192])
// Window (16,9,9): depth valid (96->81), h/w zero-padded +-4.
// K1 = depth sliding sum (regs, prefetched) + two-stage 3+3 w-box in float4
// LDS, two od-outputs per barrier round, raw barriers (round-10 known-good).
// K2 = h sliding box, full unroll + static 8-deep ring; CH=12 (grid 2592,
// ~10 blocks/CU); loss partials -> 64 spread slots (atomic line-spread).
// K3 = slot reduce.

constexpr int N = 2, D = 96, H = 192, W = 192;
constexpr int OD = 81;            // D - 16 + 1
constexpr int KD = 16;
constexpr int HWp = H * W;        // 36864
constexpr float INV_WIN = 1.0f / 1296.0f;
constexpr float EPS_NZ = 3.0590232050182579e-07f;  // e^-15
constexpr int CH = 12;            // h-chunk per block in K2 (192/12 = 16)
constexpr int ODPB = 14;          // od-range per K1 block (9 blocks/CU)

__device__ __forceinline__ unsigned bf16rne(float f) {  // f32 -> bf16 bits (RNE)
  unsigned u = __float_as_uint(f);
  return (u + 0x7fffu + ((u >> 16) & 1u)) >> 16;
}
__device__ __forceinline__ float bf16tof(unsigned h) {  // bf16 bits -> f32
  return __uint_as_float(h << 16);
}

// ---------------------------------------------------------------------------
// K1. Per (n,h) row, stream depth with running 5-ch sums; snapshots for od
// and od+1 go to LDS buffer sets 0/1; one {B1,stage1x2,B2,stage2x2} round
// serves both. Entering/leaving slices for the NEXT pair prefetched during
// the current round. ws layout: [n][odi][h][w] x 3 uints (bf16 pairs).
__global__ __launch_bounds__(192)
void k_dw(const float* __restrict__ I, const float* __restrict__ J,
          unsigned* __restrict__ ws, int od0, int c, int odcStride) {
  const int h = blockIdx.x;
  const int n = blockIdx.z;
  const int os = od0 + blockIdx.y * ODPB;
  int oe = od0 + c; if (os + ODPB < oe) oe = os + ODPB;
  if (os >= oe) return;
  const int w = threadIdx.x;

  __shared__ float4 x4[2][W + 8];
  __shared__ float  x1[2][W + 8];
  __shared__ float4 a4[2][W + 8];
  __shared__ float  a1[2][W + 8];

  if (w < 4) {
    x4[0][w] = make_float4(0.f,0.f,0.f,0.f); x1[0][w] = 0.f;
    x4[1][w] = make_float4(0.f,0.f,0.f,0.f); x1[1][w] = 0.f;
  }
  if (w >= W - 4) {
    x4[0][w + 8] = make_float4(0.f,0.f,0.f,0.f); x1[0][w + 8] = 0.f;
    x4[1][w + 8] = make_float4(0.f,0.f,0.f,0.f); x1[1][w + 8] = 0.f;
  }
  __syncthreads();   // one safe barrier before the pipelined loop

  const size_t colBase = ((size_t)n * D * H + h) * (size_t)W + w;
  const float* Ip = I + colBase;
  const float* Jp = J + colBase;
  unsigned* wbase = ws + ((size_t)n * odcStride * HWp + (size_t)h * W + w) * 3;

  // extra a3 position for halo coverage (pe in 1..3 and 196..198)
  int pe = -1;
  if (w < 3) pe = w + 1;
  else if (w >= W - 3) pe = w + 7;
  const int p = 4 + w;

  // warm-up: accumulate slices [os, os+KD-2] (15 slices)
  float sI = 0.f, sJ = 0.f, sII = 0.f, sJJ = 0.f, sIJ = 0.f;
  for (int d = os; d < os + KD - 1; ++d) {
    const float iv = Ip[(size_t)d * HWp];
    const float jv = Jp[(size_t)d * HWp];
    sI += iv; sJ += jv;
    sII += iv * iv; sJJ += jv * jv; sIJ += iv * jv;
  }

  // prefetch first pair: entering od+15 / od+16, leaving od / od+1
  int od = os;
  float eI0 = Ip[(size_t)(od + KD - 1) * HWp];
  float eJ0 = Jp[(size_t)(od + KD - 1) * HWp];
  float lI0 = Ip[(size_t)od * HWp];
  float lJ0 = Jp[(size_t)od * HWp];
  float eI1 = 0.f, eJ1 = 0.f, lI1 = 0.f, lJ1 = 0.f;
  if (od + 1 < oe) {
    eI1 = Ip[(size_t)(od + KD) * HWp];
    eJ1 = Jp[(size_t)(od + KD) * HWp];
    lI1 = Ip[(size_t)(od + 1) * HWp];
    lJ1 = Jp[(size_t)(od + 1) * HWp];
  }

  while (od < oe) {
    const bool two = (od + 1 < oe);
    const float ceI0 = eI0, ceJ0 = eJ0, clI0 = lI0, clJ0 = lJ0;
    const float ceI1 = eI1, ceJ1 = eJ1, clI1 = lI1, clJ1 = lJ1;
    // prefetch next pair (issued now, awaited next iteration)
    const int odn = od + 2;
    if (odn < oe) {
      eI0 = Ip[(size_t)(odn + KD - 1) * HWp];
      eJ0 = Jp[(size_t)(odn + KD - 1) * HWp];
      lI0 = Ip[(size_t)odn * HWp];
      lJ0 = Jp[(size_t)odn * HWp];
      if (odn + 1 < oe) {
        eI1 = Ip[(size_t)(odn + KD) * HWp];
        eJ1 = Jp[(size_t)(odn + KD) * HWp];
        lI1 = Ip[(size_t)(odn + 1) * HWp];
        lJ1 = Jp[(size_t)(odn + 1) * HWp];
      }
    }
    // snapshot od into buffer 0
    sI += ceI0; sJ += ceJ0;
    sII += ceI0 * ceI0; sJJ += ceJ0 * ceJ0; sIJ += ceI0 * ceJ0;
    x4[0][p] = make_float4(sI, sJ, sII, sJJ); x1[0][p] = sIJ;
    sI -= clI0; sJ -= clJ0;
    sII -= clI0 * clI0; sJJ -= clJ0 * clJ0; sIJ -= clI0 * clJ0;
    if (two) {  // snapshot od+1 into buffer 1
      sI += ceI1; sJ += ceJ1;
      sII += ceI1 * ceI1; sJJ += ceJ1 * ceJ1; sIJ += ceI1 * ceJ1;
      x4[1][p] = make_float4(sI, sJ, sII, sJJ); x1[1][p] = sIJ;
      sI -= clI1; sJ -= clJ1;
      sII -= clI1 * clI1; sJJ -= clJ1 * clJ1; sIJ -= clI1 * clJ1;
    }
    asm volatile("s_waitcnt lgkmcnt(0)" ::: "memory");
    __builtin_amdgcn_s_barrier();       // B1: x[0] (and x[1]) visible
    // stage 1: a3[p] = x[p-1]+x[p]+x[p+1], both buffers
    {
      float4 m0 = x4[0][p - 1], m1 = x4[0][p], m2 = x4[0][p + 1];
      a4[0][p] = make_float4(m0.x + m1.x + m2.x, m0.y + m1.y + m2.y,
                             m0.z + m1.z + m2.z, m0.w + m1.w + m2.w);
      a1[0][p] = x1[0][p - 1] + x1[0][p] + x1[0][p + 1];
      if (pe >= 0) {
        float4 e0 = x4[0][pe - 1], e1 = x4[0][pe], e2 = x4[0][pe + 1];
        a4[0][pe] = make_float4(e0.x + e1.x + e2.x, e0.y + e1.y + e2.y,
                                e0.z + e1.z + e2.z, e0.w + e1.w + e2.w);
        a1[0][pe] = x1[0][pe - 1] + x1[0][pe] + x1[0][pe + 1];
      }
    }
    if (two) {
      float4 m0 = x4[1][p - 1], m1 = x4[1][p], m2 = x4[1][p + 1];
      a4[1][p] = make_float4(m0.x + m1.x + m2.x, m0.y + m1.y + m2.y,
                             m0.z + m1.z + m2.z, m0.w + m1.w + m2.w);
      a1[1][p] = x1[1][p - 1] + x1[1][p] + x1[1][p + 1];
      if (pe >= 0) {
        float4 e0 = x4[1][pe - 1], e1 = x4[1][pe], e2 = x4[1][pe + 1];
        a4[1][pe] = make_float4(e0.x + e1.x + e2.x, e0.y + e1.y + e2.y,
                                e0.z + e1.z + e2.z, e0.w + e1.w + e2.w);
        a1[1][pe] = x1[1][pe - 1] + x1[1][pe] + x1[1][pe + 1];
      }
    }
    asm volatile("s_waitcnt lgkmcnt(0)" ::: "memory");
    __builtin_amdgcn_s_barrier();       // B2: a[0] (and a[1]) visible
    // stage 2: S9 = a3[p-3]+a3[p]+a3[p+3]; store
    {
      float4 b0 = a4[0][p - 3], b1 = a4[0][p], b2 = a4[0][p + 3];
      const float r0 = b0.x + b1.x + b2.x;
      const float r1 = b0.y + b1.y + b2.y;
      const float r2 = b0.z + b1.z + b2.z;
      const float r3 = b0.w + b1.w + b2.w;
      const float r4 = a1[0][p - 3] + a1[0][p] + a1[0][p + 3];
      unsigned* o = wbase + (size_t)(od - od0) * HWp * 3;
      *(uint3*)o = make_uint3(bf16rne(r0) | (bf16rne(r1) << 16),
                              bf16rne(r2) | (bf16rne(r3) << 16),
                              bf16rne(r4));
    }
    if (two) {
      float4 b0 = a4[1][p - 3], b1 = a4[1][p], b2 = a4[1][p + 3];
      const float r0 = b0.x + b1.x + b2.x;
      const float r1 = b0.y + b1.y + b2.y;
      const float r2 = b0.z + b1.z + b2.z;
      const float r3 = b0.w + b1.w + b2.w;
      const float r4 = a1[1][p - 3] + a1[1][p] + a1[1][p + 3];
      unsigned* o = wbase + (size_t)(od + 1 - od0) * HWp * 3;
      *(uint3*)o = make_uint3(bf16rne(r0) | (bf16rne(r1) << 16),
                              bf16rne(r2) | (bf16rne(r3) << 16),
                              bf16rne(r4));
    }
    od += 2;
  }
}

// ---------------------------------------------------------------------------
// K2: 9-wide h box via fully-unrolled stream with an 8-deep static ring
// (no subtract re-loads) + one-ahead prefetch; cc formula + loss reduction.
// Loss partial -> one of 32 spread slots per batch (atomic line-spread).
// Block: 192 threads = w-row, grid (od, h-chunk of 12, n) = 2592 blocks.
__global__ __launch_bounds__(192)
void k_hcc(const unsigned* __restrict__ ws, float* __restrict__ cc,
           float* __restrict__ acc, int od0, int odcStride) {
  const int odi = blockIdx.x;
  const int od = od0 + odi;
  const int h0 = blockIdx.y * CH;
  const int n = blockIdx.z;
  const int w = threadIdx.x;
  const unsigned* base =
      ws + ((size_t)n * odcStride * HWp + (size_t)odi * HWp + w) * 3;
  float* ccp = cc + ((size_t)n * OD + od) * (size_t)HWp + w;

  float s0 = 0.f, s1 = 0.f, s2 = 0.f, s3 = 0.f, s4 = 0.f;
  float lsum = 0.f;
  uint3 hist[8];
  const uint3 z3 = make_uint3(0u, 0u, 0u);

  // prefetch t=0 row
  uint3 vN = z3;
  {
    const int hin = h0 - 4;
    if (hin >= 0) vN = *(const uint3*)(base + (size_t)hin * W * 3);
  }
#pragma unroll
  for (int t = 0; t < CH + 8; ++t) {
    const uint3 v = vN;
    // prefetch next row
    if (t + 1 < CH + 8) {
      const int hn = h0 - 4 + t + 1;
      vN = (hn >= 0 && hn < H) ? *(const uint3*)(base + (size_t)hn * W * 3) : z3;
    }
    s0 += bf16tof(v.x & 0xffffu); s1 += bf16tof(v.x >> 16);
    s2 += bf16tof(v.y & 0xffffu); s3 += bf16tof(v.y >> 16);
    s4 += bf16tof(v.z & 0xffffu);
    if (t >= 8) {
      const int h = h0 + t - 8;
      const float cross = s4 - s0 * s1 * INV_WIN;
      const float vI = s2 - s0 * s0 * INV_WIN;
      const float vJ = s3 - s1 * s1 * INV_WIN;
      const float prod = vI * vJ;
      const float c = (prod > EPS_NZ) ? (cross * cross) / (prod + EPS_NZ)
                                      : 1.0f / (1.0f + EPS_NZ);
      ccp[(size_t)h * W] = c;
      lsum += c;
      const uint3 q = hist[t & 7];       // row that entered 8 steps ago
      s0 -= bf16tof(q.x & 0xffffu); s1 -= bf16tof(q.x >> 16);
      s2 -= bf16tof(q.y & 0xffffu); s3 -= bf16tof(q.y >> 16);
      s4 -= bf16tof(q.z & 0xffffu);
    }
    hist[t & 7] = v;                     // static index (full unroll)
  }
  __shared__ float red[3];
#pragma unroll
  for (int off = 32; off > 0; off >>= 1) lsum += __shfl_xor(lsum, off, 64);
  if ((threadIdx.x & 63) == 0) red[threadIdx.x >> 6] = lsum;
  __syncthreads();
  if (threadIdx.x == 0)
    atomicAdd(acc + n * 32 + (odi & 31), red[0] + red[1] + red[2]);
}

// ---------------------------------------------------------------------------
// K3: reduce the 64 spread slots (32 per batch) -> loss.
__global__ void k_fin(const float* __restrict__ acc, float* __restrict__ out) {
  const int t = threadIdx.x;            // 64 threads
  float v = acc[t];                     // slots [n*32 + k]
#pragma unroll
  for (int off = 16; off > 0; off >>= 1) v += __shfl_xor(v, off, 32);
  if (t == 0)  out[0] = 1.0f - v * (1.0f / 2985984.0f);
  if (t == 32) out[1] = 1.0f - v * (1.0f / 2985984.0f);
}

// ---------------------------------------------------------------------------
extern "C" void kernel_launch(void* const* d_in, const int* in_sizes, int n_in,
                              void* d_out, int out_size, void* d_ws,
                              size_t ws_size, hipStream_t stream) {
  const float* I = (const float*)d_in[0];
  const float* J = (const float*)d_in[1];
  float* out = (float*)d_out;
  float* acc = (float*)d_ws;                       // 64 fp32 spread slots
  unsigned* planes = (unsigned*)((char*)d_ws + 256);

  hipMemsetAsync(d_ws, 0, 64 * sizeof(float), stream);

  // adaptive od-chunking: packed voxel = 12B, two n-slabs
  const size_t perOdPerN = (size_t)HWp * 12;       // 442368 B
  size_t avail = (ws_size > 256) ? (ws_size - 256) : 0;
  long long odcMax = (long long)(avail / (2 * perOdPerN));
  if (odcMax < 1) odcMax = 1;
  if (odcMax > OD) odcMax = OD;
  const int odc = (int)odcMax;                     // slab stride (od entries)

  float* ccOut = out + 2;
  for (int od0 = 0; od0 < OD; od0 += odc) {
    const int c = (odc < OD - od0) ? odc : (OD - od0);
    const int S = (c + ODPB - 1) / ODPB;
    hipLaunchKernelGGL(k_dw, dim3(H, S, N), dim3(192), 0, stream,
                       I, J, planes, od0, c, odc);
    hipLaunchKernelGGL(k_hcc, dim3(c, H / CH, N), dim3(192), 0, stream,
                       planes, ccOut, acc, od0, odc);
  }
  hipLaunchKernelGGL(k_fin, dim3(1), dim3(64), 0, stream, acc, out);
}

// Round 19
// 63.827 us; speedup vs baseline: 1.2597x; 1.1143x over previous
//
#include <hip/hip_runtime.h>

// LocalCrossCorrelation3D: I,J (2,1,96,192,192) fp32 -> (loss[2], cc[2,81,192,192])
// Window (16,9,9): depth valid (96->81), h/w zero-padded +-4.
// K1 = depth sliding sum + two-stage 3+3 w-box in float4 LDS, two od-outputs
// per barrier round, raw barriers; PREFETCH DEPTH 2 ROUNDS (16 loads in
// flight/wave — Little's-law fix). ws = AoS uint3 bf16 (12B/voxel).
// K2 = h sliding box, full unroll + static ring, CH=24, spread-slot atomics.
// K3 = slot reduce.

constexpr int N = 2, D = 96, H = 192, W = 192;
constexpr int OD = 81;            // D - 16 + 1
constexpr int KD = 16;
constexpr int HWp = H * W;        // 36864
constexpr float INV_WIN = 1.0f / 1296.0f;
constexpr float EPS_NZ = 3.0590232050182579e-07f;  // e^-15
constexpr int CH = 24;            // h-chunk per block in K2 (192/24 = 8)
constexpr int ODPB = 14;          // od-range per K1 block (9 blocks/CU)

__device__ __forceinline__ unsigned bf16rne(float f) {  // f32 -> bf16 bits (RNE)
  unsigned u = __float_as_uint(f);
  return (u + 0x7fffu + ((u >> 16) & 1u)) >> 16;
}
__device__ __forceinline__ float bf16tof(unsigned h) {  // bf16 bits -> f32
  return __uint_as_float(h << 16);
}

// ---------------------------------------------------------------------------
// K1. Per (n,h) row, stream depth with running 5-ch sums; snapshots for od
// and od+1 go to LDS buffer sets 0/1; one {B1,stage1x2,B2,stage2x2} round
// serves both. TWO rounds of enter/leave slices prefetched (slots A/B) so
// ~16 loads stay in flight per wave across the barrier section.
// ws layout: [n][odi][h][w] x 3 uints (bf16 pairs: (s0,s1),(s2,s3),(s4,_)).
__global__ __launch_bounds__(192)
void k_dw(const float* __restrict__ I, const float* __restrict__ J,
          unsigned* __restrict__ ws, int od0, int c, int odcStride) {
  const int h = blockIdx.x;
  const int n = blockIdx.z;
  const int os = od0 + blockIdx.y * ODPB;
  int oe = od0 + c; if (os + ODPB < oe) oe = os + ODPB;
  if (os >= oe) return;
  const int w = threadIdx.x;

  __shared__ float4 x4[2][W + 8];
  __shared__ float  x1[2][W + 8];
  __shared__ float4 a4[2][W + 8];
  __shared__ float  a1[2][W + 8];

  if (w < 4) {
    x4[0][w] = make_float4(0.f,0.f,0.f,0.f); x1[0][w] = 0.f;
    x4[1][w] = make_float4(0.f,0.f,0.f,0.f); x1[1][w] = 0.f;
  }
  if (w >= W - 4) {
    x4[0][w + 8] = make_float4(0.f,0.f,0.f,0.f); x1[0][w + 8] = 0.f;
    x4[1][w + 8] = make_float4(0.f,0.f,0.f,0.f); x1[1][w + 8] = 0.f;
  }
  __syncthreads();   // one safe barrier before the pipelined loop

  const size_t colBase = ((size_t)n * D * H + h) * (size_t)W + w;
  const float* Ip = I + colBase;
  const float* Jp = J + colBase;
  unsigned* wbase = ws + ((size_t)n * odcStride * HWp + (size_t)h * W + w) * 3;

  // extra a3 position for halo coverage (pe in 1..3 and 196..198)
  int pe = -1;
  if (w < 3) pe = w + 1;
  else if (w >= W - 3) pe = w + 7;
  const int p = 4 + w;

  // warm-up: accumulate slices [os, os+KD-2] (15 slices)
  float sI = 0.f, sJ = 0.f, sII = 0.f, sJJ = 0.f, sIJ = 0.f;
  for (int d = os; d < os + KD - 1; ++d) {
    const float iv = Ip[(size_t)d * HWp];
    const float jv = Jp[(size_t)d * HWp];
    sI += iv; sJ += jv;
    sII += iv * iv; sJJ += jv * jv; sIJ += iv * jv;
  }

  // ISSUE loads for the round starting at od=O into the given slot vars.
#define ISSUE(eA,fA,gA,hA_,eB,fB,gB,hB_, O)                                  \
  { const int _o = (O);                                                      \
    if (_o < oe) {                                                           \
      eA = Ip[(size_t)(_o + KD - 1) * HWp];                                  \
      fA = Jp[(size_t)(_o + KD - 1) * HWp];                                  \
      gA = Ip[(size_t)_o * HWp];                                             \
      hA_ = Jp[(size_t)_o * HWp];                                            \
      if (_o + 1 < oe) {                                                     \
        eB = Ip[(size_t)(_o + KD) * HWp];                                    \
        fB = Jp[(size_t)(_o + KD) * HWp];                                    \
        gB = Ip[(size_t)(_o + 1) * HWp];                                     \
        hB_ = Jp[(size_t)(_o + 1) * HWp];                                    \
      } } }

  // COMPUTE the 2-od round at od=O, consuming the slot vars (by value).
#define COMPUTE(O, eA,fA,gA,hA_,eB,fB,gB,hB_)                                \
  { const int _od = (O);                                                     \
    const bool two = (_od + 1 < oe);                                         \
    sI += eA; sJ += fA;                                                      \
    sII += eA * eA; sJJ += fA * fA; sIJ += eA * fA;                          \
    x4[0][p] = make_float4(sI, sJ, sII, sJJ); x1[0][p] = sIJ;                \
    sI -= gA; sJ -= hA_;                                                     \
    sII -= gA * gA; sJJ -= hA_ * hA_; sIJ -= gA * hA_;                       \
    if (two) {                                                               \
      sI += eB; sJ += fB;                                                    \
      sII += eB * eB; sJJ += fB * fB; sIJ += eB * fB;                        \
      x4[1][p] = make_float4(sI, sJ, sII, sJJ); x1[1][p] = sIJ;              \
      sI -= gB; sJ -= hB_;                                                   \
      sII -= gB * gB; sJJ -= hB_ * hB_; sIJ -= gB * hB_;                     \
    }                                                                        \
    asm volatile("s_waitcnt lgkmcnt(0)" ::: "memory");                       \
    __builtin_amdgcn_s_barrier();       /* B1: x visible */                  \
    {                                                                        \
      float4 m0 = x4[0][p - 1], m1 = x4[0][p], m2 = x4[0][p + 1];            \
      a4[0][p] = make_float4(m0.x + m1.x + m2.x, m0.y + m1.y + m2.y,         \
                             m0.z + m1.z + m2.z, m0.w + m1.w + m2.w);        \
      a1[0][p] = x1[0][p - 1] + x1[0][p] + x1[0][p + 1];                     \
      if (pe >= 0) {                                                         \
        float4 e0 = x4[0][pe - 1], e1 = x4[0][pe], e2 = x4[0][pe + 1];       \
        a4[0][pe] = make_float4(e0.x + e1.x + e2.x, e0.y + e1.y + e2.y,      \
                                e0.z + e1.z + e2.z, e0.w + e1.w + e2.w);     \
        a1[0][pe] = x1[0][pe - 1] + x1[0][pe] + x1[0][pe + 1];               \
      }                                                                      \
    }                                                                        \
    if (two) {                                                               \
      float4 m0 = x4[1][p - 1], m1 = x4[1][p], m2 = x4[1][p + 1];            \
      a4[1][p] = make_float4(m0.x + m1.x + m2.x, m0.y + m1.y + m2.y,         \
                             m0.z + m1.z + m2.z, m0.w + m1.w + m2.w);        \
      a1[1][p] = x1[1][p - 1] + x1[1][p] + x1[1][p + 1];                     \
      if (pe >= 0) {                                                         \
        float4 e0 = x4[1][pe - 1], e1 = x4[1][pe], e2 = x4[1][pe + 1];       \
        a4[1][pe] = make_float4(e0.x + e1.x + e2.x, e0.y + e1.y + e2.y,      \
                                e0.z + e1.z + e2.z, e0.w + e1.w + e2.w);     \
        a1[1][pe] = x1[1][pe - 1] + x1[1][pe] + x1[1][pe + 1];               \
      }                                                                      \
    }                                                                        \
    asm volatile("s_waitcnt lgkmcnt(0)" ::: "memory");                       \
    __builtin_amdgcn_s_barrier();       /* B2: a visible */                  \
    {                                                                        \
      float4 b0 = a4[0][p - 3], b1 = a4[0][p], b2 = a4[0][p + 3];            \
      const float r0 = b0.x + b1.x + b2.x;                                   \
      const float r1 = b0.y + b1.y + b2.y;                                   \
      const float r2 = b0.z + b1.z + b2.z;                                   \
      const float r3 = b0.w + b1.w + b2.w;                                   \
      const float r4 = a1[0][p - 3] + a1[0][p] + a1[0][p + 3];               \
      unsigned* o = wbase + (size_t)(_od - od0) * HWp * 3;                   \
      *(uint3*)o = make_uint3(bf16rne(r0) | (bf16rne(r1) << 16),             \
                              bf16rne(r2) | (bf16rne(r3) << 16),             \
                              bf16rne(r4));                                  \
    }                                                                        \
    if (two) {                                                               \
      float4 b0 = a4[1][p - 3], b1 = a4[1][p], b2 = a4[1][p + 3];            \
      const float r0 = b0.x + b1.x + b2.x;                                   \
      const float r1 = b0.y + b1.y + b2.y;                                   \
      const float r2 = b0.z + b1.z + b2.z;                                   \
      const float r3 = b0.w + b1.w + b2.w;                                   \
      const float r4 = a1[1][p - 3] + a1[1][p] + a1[1][p + 3];               \
      unsigned* o = wbase + (size_t)(_od + 1 - od0) * HWp * 3;               \
      *(uint3*)o = make_uint3(bf16rne(r0) | (bf16rne(r1) << 16),             \
                              bf16rne(r2) | (bf16rne(r3) << 16),             \
                              bf16rne(r4));                                  \
    } }

  // 2-round-deep prefetch: slots A (even rounds) and B (odd rounds)
  float eA0=0,fA0=0,gA0=0,hA0=0, eA1=0,fA1=0,gA1=0,hA1=0;
  float eB0=0,fB0=0,gB0=0,hB0=0, eB1=0,fB1=0,gB1=0,hB1=0;
  ISSUE(eA0,fA0,gA0,hA0,eA1,fA1,gA1,hA1, os)
  ISSUE(eB0,fB0,gB0,hB0,eB1,fB1,gB1,hB1, os + 2)

  for (int od = os; od < oe; od += 4) {
    COMPUTE(od, eA0,fA0,gA0,hA0,eA1,fA1,gA1,hA1)
    ISSUE(eA0,fA0,gA0,hA0,eA1,fA1,gA1,hA1, od + 4)
    if (od + 2 < oe) {
      COMPUTE(od + 2, eB0,fB0,gB0,hB0,eB1,fB1,gB1,hB1)
      ISSUE(eB0,fB0,gB0,hB0,eB1,fB1,gB1,hB1, od + 6)
    }
  }
#undef ISSUE
#undef COMPUTE
}

// ---------------------------------------------------------------------------
// K2: 9-wide h box via fully-unrolled stream with an 8-deep static ring
// (no subtract re-loads) + one-ahead prefetch; cc formula + loss reduction.
// Loss partial -> one of 32 spread slots per batch (atomic line-spread).
// Block: 192 threads = w-row, grid (od, h-chunk of 24, n).
__global__ __launch_bounds__(192)
void k_hcc(const unsigned* __restrict__ ws, float* __restrict__ cc,
           float* __restrict__ acc, int od0, int odcStride) {
  const int odi = blockIdx.x;
  const int od = od0 + odi;
  const int h0 = blockIdx.y * CH;
  const int n = blockIdx.z;
  const int w = threadIdx.x;
  const unsigned* base =
      ws + ((size_t)n * odcStride * HWp + (size_t)odi * HWp + w) * 3;
  float* ccp = cc + ((size_t)n * OD + od) * (size_t)HWp + w;

  float s0 = 0.f, s1 = 0.f, s2 = 0.f, s3 = 0.f, s4 = 0.f;
  float lsum = 0.f;
  uint3 hist[8];
  const uint3 z3 = make_uint3(0u, 0u, 0u);

  // prefetch t=0 row
  uint3 vN = z3;
  {
    const int hin = h0 - 4;
    if (hin >= 0) vN = *(const uint3*)(base + (size_t)hin * W * 3);
  }
#pragma unroll
  for (int t = 0; t < CH + 8; ++t) {
    const uint3 v = vN;
    // prefetch next row
    if (t + 1 < CH + 8) {
      const int hn = h0 - 4 + t + 1;
      vN = (hn >= 0 && hn < H) ? *(const uint3*)(base + (size_t)hn * W * 3) : z3;
    }
    s0 += bf16tof(v.x & 0xffffu); s1 += bf16tof(v.x >> 16);
    s2 += bf16tof(v.y & 0xffffu); s3 += bf16tof(v.y >> 16);
    s4 += bf16tof(v.z & 0xffffu);
    if (t >= 8) {
      const int h = h0 + t - 8;
      const float cross = s4 - s0 * s1 * INV_WIN;
      const float vI = s2 - s0 * s0 * INV_WIN;
      const float vJ = s3 - s1 * s1 * INV_WIN;
      const float prod = vI * vJ;
      const float c = (prod > EPS_NZ) ? (cross * cross) / (prod + EPS_NZ)
                                      : 1.0f / (1.0f + EPS_NZ);
      ccp[(size_t)h * W] = c;
      lsum += c;
      const uint3 q = hist[t & 7];       // row that entered 8 steps ago
      s0 -= bf16tof(q.x & 0xffffu); s1 -= bf16tof(q.x >> 16);
      s2 -= bf16tof(q.y & 0xffffu); s3 -= bf16tof(q.y >> 16);
      s4 -= bf16tof(q.z & 0xffffu);
    }
    hist[t & 7] = v;                     // static index (full unroll)
  }
  __shared__ float red[3];
#pragma unroll
  for (int off = 32; off > 0; off >>= 1) lsum += __shfl_xor(lsum, off, 64);
  if ((threadIdx.x & 63) == 0) red[threadIdx.x >> 6] = lsum;
  __syncthreads();
  if (threadIdx.x == 0)
    atomicAdd(acc + n * 32 + (odi & 31), red[0] + red[1] + red[2]);
}

// ---------------------------------------------------------------------------
// K3: reduce the 64 spread slots (32 per batch) -> loss.
__global__ void k_fin(const float* __restrict__ acc, float* __restrict__ out) {
  const int t = threadIdx.x;            // 64 threads
  float v = acc[t];                     // slots [n*32 + k]
#pragma unroll
  for (int off = 16; off > 0; off >>= 1) v += __shfl_xor(v, off, 32);
  if (t == 0)  out[0] = 1.0f - v * (1.0f / 2985984.0f);
  if (t == 32) out[1] = 1.0f - v * (1.0f / 2985984.0f);
}

// ---------------------------------------------------------------------------
extern "C" void kernel_launch(void* const* d_in, const int* in_sizes, int n_in,
                              void* d_out, int out_size, void* d_ws,
                              size_t ws_size, hipStream_t stream) {
  const float* I = (const float*)d_in[0];
  const float* J = (const float*)d_in[1];
  float* out = (float*)d_out;
  float* acc = (float*)d_ws;                       // 64 fp32 spread slots
  unsigned* planes = (unsigned*)((char*)d_ws + 256);

  hipMemsetAsync(d_ws, 0, 64 * sizeof(float), stream);

  // adaptive od-chunking: packed voxel = 12B, two n-slabs
  const size_t perOdPerN = (size_t)HWp * 12;       // 442368 B
  size_t avail = (ws_size > 256) ? (ws_size - 256) : 0;
  long long odcMax = (long long)(avail / (2 * perOdPerN));
  if (odcMax < 1) odcMax = 1;
  if (odcMax > OD) odcMax = OD;
  const int odc = (int)odcMax;                     // slab stride (od entries)

  float* ccOut = out + 2;
  for (int od0 = 0; od0 < OD; od0 += odc) {
    const int c = (odc < OD - od0) ? odc : (OD - od0);
    const int S = (c + ODPB - 1) / ODPB;
    hipLaunchKernelGGL(k_dw, dim3(H, S, N), dim3(192), 0, stream,
                       I, J, planes, od0, c, odc);
    hipLaunchKernelGGL(k_hcc, dim3(c, H / CH, N), dim3(192), 0, stream,
                       planes, ccOut, acc, od0, odc);
  }
  hipLaunchKernelGGL(k_fin, dim3(1), dim3(64), 0, stream, acc, out);
}